// Round 4
// baseline (142.306 us; speedup 1.0000x reference)
//
#include <hip/hip_runtime.h>
#include <cmath>

#define BB   8
#define NPIX 256
#define MM   8192
#define NCP  24576
#define NCA  24576
#define EPSF 1e-16f

#define KC   32    // K-chunk (y's per chunk) = one MFMA K-step
#define TMB  64    // m's per block
#define NT   256   // threads per block (4 waves, 1 wave/SIMD)

// ---- d_out layout (floats)
#define VIS_OFF    0
#define VISAMP_OFF (BB * 2 * MM)            // 131072
#define CPH_OFF    (VISAMP_OFF + BB * MM)   // 196608
#define LCA_OFF    (CPH_OFF + BB * NCP)     // 393216

typedef __bf16 bf16x8 __attribute__((ext_vector_type(8)));
typedef float  f32x4  __attribute__((ext_vector_type(4)));

// Window layout for B: element (row,k) -> (row>>4)*512 + (k>>3)*128 +
// (row&15)*8 + (k&7). 16 B lane stride within each 16-lane phase -> 2-way
// bank aliasing only (free, m136).
// SESSION RULES (hard-won):
//  - no cross-kernel dataflow through d_ws (R5/R6); d_out is proven.
//  - NUMERICS: full 3-term split mandatory (R12: 2-term -> cphase 361 deg).
//  - R18: dbuf+1-barrier regressed (lgkmcnt drains staging writes before
//    MFMA reads). R2: 2 co-resident lockstep blocks regressed (no overlap,
//    doubled staging). R3: in-register A = neutral (A-LDS never critical).
//    => bottleneck is strict phase serialization WITHIN the wave.
//  - THIS ROUND: single-wave ILP pipeline. NT=256/TMB=64 (R2-validated
//    math) + launch_bounds(256,1) -> 1 wave/SIMD -> 512-reg budget.
//    Next-chunk img loads + A rotor + B convert live in REGISTERS and sit
//    between the barriers WITH the MFMA loop -> scheduler hides them in
//    the MFMA pipe shadow. Single LDS buffer; ds_writes stay outside the
//    MFMA read region (no lgkmcnt drain: R18-safe). 2 barriers/chunk.
//  - WRITE_SIZE is the spill tripwire (768 KB = clean).
//  - residual ~57 us outside the vis kernel is harness-fixed; vis is the
//    only lever.
#define WIDX(row, k8) (((row) >> 4) * 512 + (k8) * 128 + ((row) & 15) * 8)

// range reduction: theta == k*n (mod 2pi) in [-pi,pi] (keeps sincosf fast).
__device__ __forceinline__ float red2pi(float k, float n)
{
    const double t = (double)k * (double)n * 0.15915494309189535;  // /(2pi)
    const double f = t - rint(t);
    return (float)(f * 6.283185307179586);
}

// Block: 64 m's x 256 x's x 1 batch, 4 waves. Ev via per-lane rotor
// recurrences directly in MFMA A-fragment layout (row=w*16+ln15, oct=q).
// 3-term split MFMA (hh, hl, lh) per plane. Software-pipelined chunks.
__global__ __launch_bounds__(NT, 1)
void nufft_vis_mfma(const float* __restrict__ images,
                    const float* __restrict__ ktraj,
                    const float* __restrict__ pulsefac,
                    float* __restrict__ out)
{
    __shared__ __align__(16) __bf16 sBh[NPIX * KC];   // 16 KB img hi
    __shared__ __align__(16) __bf16 sBl[NPIX * KC];   // 16 KB img lo

    const int tid  = threadIdx.x;
    const int m0   = blockIdx.x * TMB;
    const int b    = blockIdx.y;
    const int lane = tid & 63;
    const int w    = tid >> 6;        // wave 0..3
    const int ln15 = lane & 15;
    const int q    = lane >> 4;       // k-octet 0..3

    // ---- A rotor state: lane owns Ev row (m0 + w*16 + ln15), k-octet q.
    const float kvm = ktraj[m0 + w * 16 + ln15];
    float r1s, r1c, r32s, r32c, as_, ac_;
    sincosf(kvm, &r1s, &r1c);                          // rot1: |kvm| <= pi
    sincosf(red2pi(kvm, 32.0f), &r32s, &r32c);         // rot32
    sincosf(red2pi(kvm, (float)(q * 8 - 128)), &as_, &ac_);  // anchor @ y0=0
    float anr = ac_, ani = -as_;

    // B staging: thread owns column x = tid (0..255), all 4 k-octets.
    const float* imgb = images + b * NPIX * NPIX + tid;

    // ---- pipeline registers
    bf16x8 fRh[2], fRl[2], fIh[2], fIl[2];   // A frags, ping-pong by chunk
    float  lv[4][8];                          // prefetched img values
    bf16x8 sbh[4], sbl[4];                    // converted B, pre-ds_write

    // gen A fragments for the next chunk into slot, advance anchor (rot32)
    auto genA = [&](int slot) {
        float er = anr, ei = ani;   // Ev = exp(-i*kv*(y-128))
        #pragma unroll
        for (int j = 0; j < 8; ++j) {
            __bf16 h = (__bf16)er;
            fRh[slot][j] = h; fRl[slot][j] = (__bf16)(er - (float)h);
            h = (__bf16)ei;
            fIh[slot][j] = h; fIl[slot][j] = (__bf16)(ei - (float)h);
            const float nr = er * r1c + ei * r1s;   // *= e^{-i*kvm}
            const float ni = ei * r1c - er * r1s;
            er = nr; ei = ni;
        }
        const float nr = anr * r32c + ani * r32s;   // anchor *= e^{-i*kv*32}
        const float ni = ani * r32c - anr * r32s;
        anr = nr; ani = ni;
    };
    auto loadB = [&](int y0) {
        #pragma unroll
        for (int oct = 0; oct < 4; ++oct)
            #pragma unroll
            for (int j = 0; j < 8; ++j)
                lv[oct][j] = imgb[(y0 + oct * 8 + j) * NPIX];
    };
    auto convB = [&]() {
        #pragma unroll
        for (int oct = 0; oct < 4; ++oct)
            #pragma unroll
            for (int j = 0; j < 8; ++j) {
                const float v = lv[oct][j];
                const __bf16 h = (__bf16)v;
                sbh[oct][j] = h; sbl[oct][j] = (__bf16)(v - (float)h);
            }
    };
    auto writeB = [&]() {
        #pragma unroll
        for (int oct = 0; oct < 4; ++oct) {
            const int bo = WIDX(tid, oct);
            *(bf16x8*)&sBh[bo] = sbh[oct];
            *(bf16x8*)&sBl[bo] = sbl[oct];
        }
    };

    f32x4 acc[2][16];                 // [0]=real plane, [1]=imag plane
    #pragma unroll
    for (int rt = 0; rt < 2; ++rt)
        #pragma unroll
        for (int ct = 0; ct < 16; ++ct)
            acc[rt][ct] = (f32x4){0.f, 0.f, 0.f, 0.f};

    // ---- prologue: chunk 0 staged
    genA(0);
    loadB(0);
    convB();
    writeB();

    #pragma unroll
    for (int c = 0; c < 8; ++c) {
        const int cur = c & 1;
        __syncthreads();              // B(c) visible in LDS
        if (c < 7) loadB((c + 1) * KC);   // issue early: hides under MFMA

        #pragma unroll
        for (int ct = 0; ct < 16; ++ct) {
            const int bro = WIDX(ct * 16 + ln15, q);
            const bf16x8 bh = *(const bf16x8*)&sBh[bro];
            const bf16x8 bl = *(const bf16x8*)&sBl[bro];
            acc[0][ct] = __builtin_amdgcn_mfma_f32_16x16x32_bf16(fRh[cur], bh, acc[0][ct], 0, 0, 0);
            acc[0][ct] = __builtin_amdgcn_mfma_f32_16x16x32_bf16(fRh[cur], bl, acc[0][ct], 0, 0, 0);
            acc[0][ct] = __builtin_amdgcn_mfma_f32_16x16x32_bf16(fRl[cur], bh, acc[0][ct], 0, 0, 0);
            acc[1][ct] = __builtin_amdgcn_mfma_f32_16x16x32_bf16(fIh[cur], bh, acc[1][ct], 0, 0, 0);
            acc[1][ct] = __builtin_amdgcn_mfma_f32_16x16x32_bf16(fIh[cur], bl, acc[1][ct], 0, 0, 0);
            acc[1][ct] = __builtin_amdgcn_mfma_f32_16x16x32_bf16(fIl[cur], bh, acc[1][ct], 0, 0, 0);
        }

        if (c < 7) {                  // next-chunk prep: MFMA-shadow VALU
            genA(cur ^ 1);
            convB();
        }
        __syncthreads();              // all reads of B(c) done
        if (c < 7) writeB();          // WAR-safe: between barriers
    }

    // ---- fused stage 2 (in-wave): kdata[b,m] = sum_x tmp[m,x] * Eu[m,x]
    // C layout: col(x within tile) = ln15, row(m within tile) = 4*q + r
    #pragma unroll
    for (int r = 0; r < 4; ++r) {
        const int m = m0 + w * 16 + q * 4 + r;
        const float ku = ktraj[MM + m];
        float s0, c0, s16, c16;
        sincosf(red2pi(ku, (float)(ln15 - 128)), &s0, &c0);
        sincosf(red2pi(ku, 16.0f), &s16, &c16);
        float er = c0, ei = -s0;       // Eu at x = ln15 - 128, step +16 per ct
        float sr = 0.f, si = 0.f;
        #pragma unroll
        for (int ct = 0; ct < 16; ++ct) {
            const float tr = acc[0][ct][r];
            const float ti = acc[1][ct][r];
            sr = fmaf(tr, er, fmaf(-ti, ei, sr));
            si = fmaf(tr, ei, fmaf(ti, er, si));
            const float nr = er * c16 + ei * s16;   // *= e^{-i*ku*16}
            const float ni = ei * c16 - er * s16;
            er = nr; ei = ni;
        }
        // reduce over the 16 lanes of this quad (masks <16 stay in-quad)
        #pragma unroll
        for (int off = 8; off >= 1; off >>= 1) {
            sr += __shfl_xor(sr, off);
            si += __shfl_xor(si, off);
        }
        if (ln15 == 0) {
            const float pr = pulsefac[m];
            const float pi = pulsefac[MM + m];
            const float vr = sr * pr - si * pi;
            const float vi = sr * pi + si * pr;
            out[b * 2 * MM + m]      = vr;
            out[b * 2 * MM + MM + m] = vi;
            out[VISAMP_OFF + b * MM + m] = sqrtf(vr * vr + vi * vi + EPSF);
        }
    }
}

// polynomial atan2 (A&S 4.4.49, err <= ~1e-5 rad), fully predicated
__device__ __forceinline__ float fast_atan2f(float y, float x)
{
    const float ax = fabsf(x), ay = fabsf(y);
    const float mx = fmaxf(ax, ay), mn = fminf(ax, ay);
    const float a  = mn / fmaxf(mx, 1e-37f);
    const float s  = a * a;
    float r = 0.0208351f;
    r = fmaf(r, s, -0.0851330f);
    r = fmaf(r, s,  0.1801410f);
    r = fmaf(r, s, -0.3302995f);
    r = fmaf(r, s,  0.9998660f);
    r *= a;
    r = (ay > ax) ? (1.57079632679f - r) : r;
    r = (x < 0.0f) ? (3.14159265359f - r) : r;
    return (y < 0.0f) ? -r : r;
}

// fused cphase + logcamp. Each block serves ONE batch (NCP % 256 == 0):
// stage that batch's vis (64 KB) into LDS, scatters hit LDS.
__global__ __launch_bounds__(256)
void gather_fused(const float* __restrict__ vis,
                  const float* __restrict__ sign,
                  const int* __restrict__ cind,
                  const int* __restrict__ caind,
                  float* __restrict__ out)
{
    __shared__ float sv[2 * MM];      // 64 KB: [0,MM)=re, [MM,2MM)=im

    const int i = blockIdx.x * 256 + threadIdx.x;
    const int b = i / NCP;
    const int n = i - b * NCP;

    {
        const float4* g4 = (const float4*)(vis + b * 2 * MM);
        float4* s4 = (float4*)sv;
        #pragma unroll
        for (int j = 0; j < (2 * MM / 4) / 256; ++j)
            s4[j * 256 + threadIdx.x] = g4[j * 256 + threadIdx.x];
    }
    __syncthreads();

    float cp = 0.f;
    #pragma unroll
    for (int k = 0; k < 3; ++k) {
        const int m = cind[k * NCP + n];
        cp += sign[k * NCP + n] * fast_atan2f(sv[MM + m], sv[m]);
    }
    out[CPH_OFF + i] = cp * 57.29577951308232f;   // 180/pi

    // logcamp = 0.5*log((p1*p2)/(p3*p4)), p = vr^2+vi^2+eps — one log call
    float p[4];
    #pragma unroll
    for (int k = 0; k < 4; ++k) {
        const int m = caind[k * NCA + n];
        const float vr = sv[m];
        const float vi = sv[MM + m];
        p[k] = vr * vr + vi * vi + EPSF;
    }
    out[LCA_OFF + i] = 0.5f * __logf((p[0] * p[1]) / (p[2] * p[3]));
}

extern "C" void kernel_launch(void* const* d_in, const int* in_sizes, int n_in,
                              void* d_out, int out_size, void* d_ws, size_t ws_size,
                              hipStream_t stream)
{
    const float* images   = (const float*)d_in[0];
    const float* ktraj    = (const float*)d_in[1];
    const float* pulsefac = (const float*)d_in[2];
    const float* csign    = (const float*)d_in[3];
    const int*   cind     = (const int*)d_in[4];
    const int*   caind    = (const int*)d_in[5];
    float* out = (float*)d_out;

    dim3 grid(MM / TMB, BB);
    nufft_vis_mfma<<<grid, NT, 0, stream>>>(images, ktraj, pulsefac, out);
    gather_fused<<<BB * NCP / 256, 256, 0, stream>>>(out, csign, cind, caind, out);
}

// Round 5
// 117.890 us; speedup vs baseline: 1.2071x; 1.2071x over previous
//
#include <hip/hip_runtime.h>
#include <cmath>

#define BB   8
#define NPIX 256
#define MM   8192
#define NCP  24576
#define NCA  24576
#define EPSF 1e-16f

#define KC   32    // K-chunk (y's per chunk) = one MFMA K-step
#define TMB  128   // m's per block
#define NT   512   // threads per block (8 waves, 2 waves/SIMD)

// ---- d_out layout (floats)
#define VIS_OFF    0
#define VISAMP_OFF (BB * 2 * MM)            // 131072
#define CPH_OFF    (VISAMP_OFF + BB * MM)   // 196608
#define LCA_OFF    (CPH_OFF + BB * NCP)     // 393216

typedef __bf16 bf16x8 __attribute__((ext_vector_type(8)));
typedef float  f32x4  __attribute__((ext_vector_type(4)));

// Window layout for B: element (row,k) -> (row>>4)*512 + (k>>3)*128 +
// (row&15)*8 + (k&7). 16 B lane stride within each 16-lane phase -> 2-way
// bank aliasing only (free, m136).
// SESSION RULES (hard-won):
//  - no cross-kernel dataflow through d_ws (R5/R6); d_out is proven.
//  - NUMERICS: full 3-term split mandatory (R12: 2-term -> cphase 361 deg).
//  - R18: dbuf+1-barrier regressed. R2: 2 co-resident lockstep blocks
//    regressed (staging duplicated, no overlap). R3: in-register A =
//    neutral (A-LDS never critical). R4: pipelined schedule at 1 wave/SIMD
//    = 86 us (occupancy loss trumps ILP; also: VALUBusy ~ MfmaUtil+4 =>
//    VALUBusy INCLUDES MFMA issue; non-MFMA VALU is small; the real cost
//    is exposed latency, partially hidden by the 2nd wave/SIMD).
//  - THIS ROUND: R3 base (NT=512, 2 waves/SIMD, proven 58.5) + R4's
//    pipelined schedule (loads for c+1 issued BEFORE MFMA(c); convert
//    after; ds_write after 2nd barrier). Staging regs live across MFMA =
//    only 16 VGPR (bhalf split) -> fits 128-VGPR budget. Numerics
//    bit-identical to R3.
//  - WRITE_SIZE is the spill tripwire (768 KB = clean).
//  - residual ~57 us outside the vis kernel is harness-fixed; vis is the
//    only lever.
#define WIDX(row, k8) (((row) >> 4) * 512 + (k8) * 128 + ((row) & 15) * 8)

// range reduction: theta == k*n (mod 2pi) in [-pi,pi] (keeps sincosf fast).
__device__ __forceinline__ float red2pi(float k, float n)
{
    const double t = (double)k * (double)n * 0.15915494309189535;  // /(2pi)
    const double f = t - rint(t);
    return (float)(f * 6.283185307179586);
}

// Block: 128 m's x 256 x's x 1 batch, 8 waves. Ev via per-lane rotor
// recurrences directly in MFMA A-fragment layout (row=w*16+ln15, oct=q).
// 3-term split MFMA (hh, hl, lh) per plane. Pipelined chunk schedule.
__global__ __launch_bounds__(NT, 2)
void nufft_vis_mfma(const float* __restrict__ images,
                    const float* __restrict__ ktraj,
                    const float* __restrict__ pulsefac,
                    float* __restrict__ out)
{
    __shared__ __align__(16) __bf16 sBh[NPIX * KC];   // 16 KB img hi
    __shared__ __align__(16) __bf16 sBl[NPIX * KC];   // 16 KB img lo

    const int tid  = threadIdx.x;
    const int m0   = blockIdx.x * TMB;
    const int b    = blockIdx.y;
    const int lane = tid & 63;
    const int w    = tid >> 6;        // wave 0..7
    const int ln15 = lane & 15;
    const int q    = lane >> 4;       // k-octet 0..3

    // ---- A rotor state: lane owns Ev row (m0 + w*16 + ln15), k-octet q.
    const float kvm = ktraj[m0 + w * 16 + ln15];
    float r1s, r1c, r32s, r32c, as_, ac_;
    sincosf(kvm, &r1s, &r1c);                          // rot1: |kvm| <= pi
    sincosf(red2pi(kvm, 32.0f), &r32s, &r32c);         // rot32
    sincosf(red2pi(kvm, (float)(q * 8 - 128)), &as_, &ac_);  // anchor @ y0=0
    float anr = ac_, ani = -as_;

    // B staging: x = tid&255, y-octet pair = (tid>>8)*2 .. +1
    const int bx    = tid & 255;
    const int bhalf = tid >> 8;       // 0..1
    const float* imgb = images + b * NPIX * NPIX + bx;

    // ---- pipeline registers
    bf16x8 fRh[2], fRl[2], fIh[2], fIl[2];   // A frags, ping-pong by chunk
    float  lv[2][8];                          // prefetched img values (16)
    bf16x8 sbh[2], sbl[2];                    // converted B, pre-ds_write

    // gen A fragments for chunk into slot, advance anchor (rot32)
    auto genA = [&](int slot) {
        float er = anr, ei = ani;   // Ev = exp(-i*kv*(y-128))
        #pragma unroll
        for (int j = 0; j < 8; ++j) {
            __bf16 h = (__bf16)er;
            fRh[slot][j] = h; fRl[slot][j] = (__bf16)(er - (float)h);
            h = (__bf16)ei;
            fIh[slot][j] = h; fIl[slot][j] = (__bf16)(ei - (float)h);
            const float nr = er * r1c + ei * r1s;   // *= e^{-i*kvm}
            const float ni = ei * r1c - er * r1s;
            er = nr; ei = ni;
        }
        const float nr = anr * r32c + ani * r32s;   // anchor *= e^{-i*kv*32}
        const float ni = ani * r32c - anr * r32s;
        anr = nr; ani = ni;
    };
    auto loadB = [&](int y0) {
        #pragma unroll
        for (int oo = 0; oo < 2; ++oo)
            #pragma unroll
            for (int j = 0; j < 8; ++j)
                lv[oo][j] = imgb[(y0 + (bhalf * 2 + oo) * 8 + j) * NPIX];
    };
    auto convB = [&]() {
        #pragma unroll
        for (int oo = 0; oo < 2; ++oo)
            #pragma unroll
            for (int j = 0; j < 8; ++j) {
                const float v = lv[oo][j];
                const __bf16 h = (__bf16)v;
                sbh[oo][j] = h; sbl[oo][j] = (__bf16)(v - (float)h);
            }
    };
    auto writeB = [&]() {
        #pragma unroll
        for (int oo = 0; oo < 2; ++oo) {
            const int bo = WIDX(bx, bhalf * 2 + oo);
            *(bf16x8*)&sBh[bo] = sbh[oo];
            *(bf16x8*)&sBl[bo] = sbl[oo];
        }
    };

    f32x4 acc[2][16];                 // [0]=real plane, [1]=imag plane
    #pragma unroll
    for (int rt = 0; rt < 2; ++rt)
        #pragma unroll
        for (int ct = 0; ct < 16; ++ct)
            acc[rt][ct] = (f32x4){0.f, 0.f, 0.f, 0.f};

    // ---- prologue: chunk 0 staged
    genA(0);
    loadB(0);
    convB();
    writeB();

    #pragma unroll
    for (int c = 0; c < 8; ++c) {
        const int cur = c & 1;
        __syncthreads();              // B(c) visible in LDS
        if (c < 7) loadB((c + 1) * KC);   // in flight across MFMA phase

        #pragma unroll
        for (int ct = 0; ct < 16; ++ct) {
            const int bro = WIDX(ct * 16 + ln15, q);
            const bf16x8 bh = *(const bf16x8*)&sBh[bro];
            const bf16x8 bl = *(const bf16x8*)&sBl[bro];
            acc[0][ct] = __builtin_amdgcn_mfma_f32_16x16x32_bf16(fRh[cur], bh, acc[0][ct], 0, 0, 0);
            acc[0][ct] = __builtin_amdgcn_mfma_f32_16x16x32_bf16(fRh[cur], bl, acc[0][ct], 0, 0, 0);
            acc[0][ct] = __builtin_amdgcn_mfma_f32_16x16x32_bf16(fRl[cur], bh, acc[0][ct], 0, 0, 0);
            acc[1][ct] = __builtin_amdgcn_mfma_f32_16x16x32_bf16(fIh[cur], bh, acc[1][ct], 0, 0, 0);
            acc[1][ct] = __builtin_amdgcn_mfma_f32_16x16x32_bf16(fIh[cur], bl, acc[1][ct], 0, 0, 0);
            acc[1][ct] = __builtin_amdgcn_mfma_f32_16x16x32_bf16(fIl[cur], bh, acc[1][ct], 0, 0, 0);
        }

        if (c < 7) {                  // next-chunk prep in the MFMA shadow
            genA(cur ^ 1);
            convB();
        }
        __syncthreads();              // all reads of B(c) done
        if (c < 7) writeB();          // WAR-safe: between barriers
    }

    // ---- fused stage 2 (in-wave): kdata[b,m] = sum_x tmp[m,x] * Eu[m,x]
    // C layout: col(x within tile) = ln15, row(m within tile) = 4*q + r
    #pragma unroll
    for (int r = 0; r < 4; ++r) {
        const int m = m0 + w * 16 + q * 4 + r;
        const float ku = ktraj[MM + m];
        float s0, c0, s16, c16;
        sincosf(red2pi(ku, (float)(ln15 - 128)), &s0, &c0);
        sincosf(red2pi(ku, 16.0f), &s16, &c16);
        float er = c0, ei = -s0;       // Eu at x = ln15 - 128, step +16 per ct
        float sr = 0.f, si = 0.f;
        #pragma unroll
        for (int ct = 0; ct < 16; ++ct) {
            const float tr = acc[0][ct][r];
            const float ti = acc[1][ct][r];
            sr = fmaf(tr, er, fmaf(-ti, ei, sr));
            si = fmaf(tr, ei, fmaf(ti, er, si));
            const float nr = er * c16 + ei * s16;   // *= e^{-i*ku*16}
            const float ni = ei * c16 - er * s16;
            er = nr; ei = ni;
        }
        // reduce over the 16 lanes of this quad (masks <16 stay in-quad)
        #pragma unroll
        for (int off = 8; off >= 1; off >>= 1) {
            sr += __shfl_xor(sr, off);
            si += __shfl_xor(si, off);
        }
        if (ln15 == 0) {
            const float pr = pulsefac[m];
            const float pi = pulsefac[MM + m];
            const float vr = sr * pr - si * pi;
            const float vi = sr * pi + si * pr;
            out[b * 2 * MM + m]      = vr;
            out[b * 2 * MM + MM + m] = vi;
            out[VISAMP_OFF + b * MM + m] = sqrtf(vr * vr + vi * vi + EPSF);
        }
    }
}

// polynomial atan2 (A&S 4.4.49, err <= ~1e-5 rad), fully predicated
__device__ __forceinline__ float fast_atan2f(float y, float x)
{
    const float ax = fabsf(x), ay = fabsf(y);
    const float mx = fmaxf(ax, ay), mn = fminf(ax, ay);
    const float a  = mn / fmaxf(mx, 1e-37f);
    const float s  = a * a;
    float r = 0.0208351f;
    r = fmaf(r, s, -0.0851330f);
    r = fmaf(r, s,  0.1801410f);
    r = fmaf(r, s, -0.3302995f);
    r = fmaf(r, s,  0.9998660f);
    r *= a;
    r = (ay > ax) ? (1.57079632679f - r) : r;
    r = (x < 0.0f) ? (3.14159265359f - r) : r;
    return (y < 0.0f) ? -r : r;
}

// fused cphase + logcamp. Each block serves ONE batch (NCP % 256 == 0):
// stage that batch's vis (64 KB) into LDS, scatters hit LDS.
__global__ __launch_bounds__(256)
void gather_fused(const float* __restrict__ vis,
                  const float* __restrict__ sign,
                  const int* __restrict__ cind,
                  const int* __restrict__ caind,
                  float* __restrict__ out)
{
    __shared__ float sv[2 * MM];      // 64 KB: [0,MM)=re, [MM,2MM)=im

    const int i = blockIdx.x * 256 + threadIdx.x;
    const int b = i / NCP;
    const int n = i - b * NCP;

    {
        const float4* g4 = (const float4*)(vis + b * 2 * MM);
        float4* s4 = (float4*)sv;
        #pragma unroll
        for (int j = 0; j < (2 * MM / 4) / 256; ++j)
            s4[j * 256 + threadIdx.x] = g4[j * 256 + threadIdx.x];
    }
    __syncthreads();

    float cp = 0.f;
    #pragma unroll
    for (int k = 0; k < 3; ++k) {
        const int m = cind[k * NCP + n];
        cp += sign[k * NCP + n] * fast_atan2f(sv[MM + m], sv[m]);
    }
    out[CPH_OFF + i] = cp * 57.29577951308232f;   // 180/pi

    // logcamp = 0.5*log((p1*p2)/(p3*p4)), p = vr^2+vi^2+eps — one log call
    float p[4];
    #pragma unroll
    for (int k = 0; k < 4; ++k) {
        const int m = caind[k * NCA + n];
        const float vr = sv[m];
        const float vi = sv[MM + m];
        p[k] = vr * vr + vi * vi + EPSF;
    }
    out[LCA_OFF + i] = 0.5f * __logf((p[0] * p[1]) / (p[2] * p[3]));
}

extern "C" void kernel_launch(void* const* d_in, const int* in_sizes, int n_in,
                              void* d_out, int out_size, void* d_ws, size_t ws_size,
                              hipStream_t stream)
{
    const float* images   = (const float*)d_in[0];
    const float* ktraj    = (const float*)d_in[1];
    const float* pulsefac = (const float*)d_in[2];
    const float* csign    = (const float*)d_in[3];
    const int*   cind     = (const int*)d_in[4];
    const int*   caind    = (const int*)d_in[5];
    float* out = (float*)d_out;

    dim3 grid(MM / TMB, BB);
    nufft_vis_mfma<<<grid, NT, 0, stream>>>(images, ktraj, pulsefac, out);
    gather_fused<<<BB * NCP / 256, 256, 0, stream>>>(out, csign, cind, caind, out);
}